// Round 5
// baseline (1968.865 us; speedup 1.0000x reference)
//
#include <hip/hip_runtime.h>
#include <math.h>

// Problem constants (B,T,E)=(4,2048,2048), NH=16, NKV=4, HD=128
constexpr int Bc   = 4;
constexpr int Tc   = 2048;
constexpr int Ec   = 2048;
constexpr int NHc  = 16;
constexpr int NKVc = 4;
constexpr int HDc  = 128;
constexpr int KVEc = NKVc * HDc; // 512

typedef __attribute__((ext_vector_type(8))) short bf16x8;
typedef __attribute__((ext_vector_type(4))) short short4v;
typedef __attribute__((ext_vector_type(4))) float f32x4;

__device__ __forceinline__ short f2bf(float f) {   // round-to-nearest-even
    union { float f; unsigned u; } v; v.f = f;
    unsigned r = v.u + 0x7FFF + ((v.u >> 16) & 1);
    return (short)(r >> 16);
}
__device__ __forceinline__ float bf2f(short s) {
    union { unsigned u; float f; } v; v.u = ((unsigned)(unsigned short)s) << 16;
    return v.f;
}
// 2^x via the hardware transcendental (v_exp_f32 computes 2^x).
// __exp2f collides with glibc math.h on this toolchain; inline asm is the
// guaranteed-single-instruction spelling.
__device__ __forceinline__ float ex2(float x) {
    float r; asm("v_exp_f32 %0, %1" : "=v"(r) : "v"(x)); return r;
}
// async global->LDS, 16B per lane; LDS dest = wave-uniform base + lane*16
__device__ __forceinline__ void gload16(const void* g, void* l) {
    __builtin_amdgcn_global_load_lds(
        (const __attribute__((address_space(1))) unsigned*)g,
        (__attribute__((address_space(3))) unsigned*)l, 16, 0, 0);
}

// ---------------------------------------------------------------------------
// Prep: x fp32 -> hi/lo bf16 (same layout)
// ---------------------------------------------------------------------------
__global__ __launch_bounds__(256)
void convert_split(const float* __restrict__ X, short* __restrict__ Xhi,
                   short* __restrict__ Xlo)
{
    int i = blockIdx.x * 256 + threadIdx.x;    // float4 index
    float4 v = ((const float4*)X)[i];
    float fv[4] = {v.x, v.y, v.z, v.w};
    short4v hi, lo;
    #pragma unroll
    for (int j = 0; j < 4; ++j) {
        hi[j] = f2bf(fv[j]);
        lo[j] = f2bf(fv[j] - bf2f(hi[j]));
    }
    ((short4v*)Xhi)[i] = hi;
    ((short4v*)Xlo)[i] = lo;
}

// ---------------------------------------------------------------------------
// Prep: W [K][N] fp32 -> WT hi (and optional lo) [N][K] bf16
// ---------------------------------------------------------------------------
__global__ __launch_bounds__(256)
void transpose_split(const float* __restrict__ W, short* __restrict__ WThi,
                     short* __restrict__ WTlo, int K, int N)
{
    __shared__ float Ls[32][33];
    const int k0 = blockIdx.x * 32, n0 = blockIdx.y * 32;
    const int t = threadIdx.x;
    const int r = t >> 3, c4 = (t & 7) << 2;
    float4 v = *(const float4*)(W + (size_t)(k0 + r) * N + n0 + c4);
    Ls[r][c4 + 0] = v.x; Ls[r][c4 + 1] = v.y;
    Ls[r][c4 + 2] = v.z; Ls[r][c4 + 3] = v.w;
    __syncthreads();
    short4v hi, lo;
    #pragma unroll
    for (int i = 0; i < 4; ++i) {
        float f = Ls[c4 + i][r];
        hi[i] = f2bf(f);
        lo[i] = f2bf(f - bf2f(hi[i]));
    }
    *(short4v*)(WThi + (size_t)(n0 + r) * K + k0 + c4) = hi;
    if (WTlo) *(short4v*)(WTlo + (size_t)(n0 + r) * K + k0 + c4) = lo;
}

// ---------------------------------------------------------------------------
// Mask -> bitmask: Mb[b][q][w] bit j = (mask[b][q][w*64+j] != 0)
// ---------------------------------------------------------------------------
__global__ __launch_bounds__(256)
void mask_bits(const int* __restrict__ mask, unsigned long long* __restrict__ Mb)
{
    const int widx = blockIdx.x * 4 + (threadIdx.x >> 6);
    const int L = threadIdx.x & 63;
    const int m = mask[(size_t)widx * 64 + L];
    unsigned long long bits = __ballot(m != 0);
    if (L == 0) Mb[widx] = bits;
}

// ---------------------------------------------------------------------------
// MFMA GEMM: C = A @ B^T + bias, 128x128 tile, BK=32.
// QOUT: epilogue writes split bf16 (Chi/Clo) instead of fp32 C — used for
// the Q projection, whose only consumer (attn) wants bf16 hi/lo fragments.
// ---------------------------------------------------------------------------
template <bool SPLIT, bool QOUT>
__global__ __launch_bounds__(256, 2)
void gemm_mfma(const short* __restrict__ Ahi, const short* __restrict__ Alo,
               const short* __restrict__ Bhi, const short* __restrict__ Blo,
               const float* __restrict__ bias, float* __restrict__ C,
               short* __restrict__ Chi, short* __restrict__ Clo,
               int M, int N, int K)
{
    __shared__ short AsH[128 * 32];
    __shared__ short BsH[128 * 32];
    __shared__ short AsL[SPLIT ? 128 * 32 : 8];
    __shared__ short BsL[SPLIT ? 128 * 32 : 8];

    const int t = threadIdx.x;
    const int w = t >> 6, L = t & 63;
    const int l16 = L & 15, quad = L >> 4;
    const int wr = w >> 1, wc = w & 1;
    const int bm = blockIdx.x * 128, bn = blockIdx.y * 128;

    const int sm = L >> 2;
    const int sq = ((L & 3) - (sm >> 2)) & 3;
    const int scol = sq * 8;

    f32x4 acc[4][4];
    #pragma unroll
    for (int mi = 0; mi < 4; ++mi)
        #pragma unroll
        for (int ni = 0; ni < 4; ++ni) acc[mi][ni] = (f32x4){0, 0, 0, 0};

    const int fxor = (quad + (l16 >> 2)) & 3;

    for (int k0 = 0; k0 < K; k0 += 32) {
        __syncthreads();
        #pragma unroll
        for (int i = 0; i < 2; ++i) {
            const int wl = w * 2 + i;
            const size_t ra = (size_t)(bm + wl * 16 + sm) * K + k0 + scol;
            const size_t rb = (size_t)(bn + wl * 16 + sm) * K + k0 + scol;
            gload16(Ahi + ra, &AsH[wl * 512]);
            gload16(Bhi + rb, &BsH[wl * 512]);
            if (SPLIT) {
                gload16(Alo + ra, &AsL[wl * 512]);
                gload16(Blo + rb, &BsL[wl * 512]);
            }
        }
        __syncthreads();

        bf16x8 ah[4], bh[4], al[4], bl[4];
        #pragma unroll
        for (int mi = 0; mi < 4; ++mi) {
            const int ch = ((wr * 4 + mi) * 64 + l16 * 4 + fxor) * 8;
            ah[mi] = *(const bf16x8*)&AsH[ch];
            if (SPLIT) al[mi] = *(const bf16x8*)&AsL[ch];
        }
        #pragma unroll
        for (int ni = 0; ni < 4; ++ni) {
            const int ch = ((wc * 4 + ni) * 64 + l16 * 4 + fxor) * 8;
            bh[ni] = *(const bf16x8*)&BsH[ch];
            if (SPLIT) bl[ni] = *(const bf16x8*)&BsL[ch];
        }
        #pragma unroll
        for (int mi = 0; mi < 4; ++mi)
            #pragma unroll
            for (int ni = 0; ni < 4; ++ni) {
                acc[mi][ni] = __builtin_amdgcn_mfma_f32_16x16x32_bf16(
                    ah[mi], bh[ni], acc[mi][ni], 0, 0, 0);
                if (SPLIT) {
                    acc[mi][ni] = __builtin_amdgcn_mfma_f32_16x16x32_bf16(
                        al[mi], bh[ni], acc[mi][ni], 0, 0, 0);
                    acc[mi][ni] = __builtin_amdgcn_mfma_f32_16x16x32_bf16(
                        ah[mi], bl[ni], acc[mi][ni], 0, 0, 0);
                }
            }
    }

    #pragma unroll
    for (int ni = 0; ni < 4; ++ni) {
        const int col = bn + wc * 64 + ni * 16 + l16;
        const float bv = bias[col];
        #pragma unroll
        for (int mi = 0; mi < 4; ++mi) {
            #pragma unroll
            for (int r = 0; r < 4; ++r) {
                const int row = bm + wr * 64 + mi * 16 + quad * 4 + r;
                const float f = acc[mi][ni][r] + bv;
                if (QOUT) {
                    const short hi = f2bf(f);
                    Chi[(size_t)row * N + col] = hi;
                    Clo[(size_t)row * N + col] = f2bf(f - bf2f(hi));
                } else {
                    C[(size_t)row * N + col] = f;
                }
            }
        }
    }
}

// ---------------------------------------------------------------------------
// RoPE for K: fp32 K2d (B,T,512) -> Khi/Klo bf16 (B,NKV,T,HD)  (unchanged)
// ---------------------------------------------------------------------------
__global__ __launch_bounds__(256)
void rope_k(const float* __restrict__ X2d, short* __restrict__ Khi,
            short* __restrict__ Klo)
{
    const int idx = blockIdx.x * 256 + threadIdx.x;
    const int j  = idx & 63;
    const int tk = (idx >> 6) & (Tc - 1);
    const int kh = (idx >> 17) & (NKVc - 1);
    const int bb = idx >> 19;
    const int row = (kh << 9) + (tk >> 2);
    const int col = ((tk & 3) << 7) + (j << 1);
    const float* src = X2d + ((size_t)bb * Tc + row) * KVEc + col;
    const float a = src[0];
    const float b = src[1];
    const float theta = powf(10000.0f, -(float)j * (1.0f / 64.0f));
    const float ang = (float)tk * theta;
    float s, c;
    sincosf(ang, &s, &c);
    const float r0 = a * c - b * s;
    const float r1 = a * s + b * c;
    const size_t off = (((size_t)bb * NKVc + kh) * Tc + tk) * HDc + (j << 1);
    short h0 = f2bf(r0), h1 = f2bf(r1);
    Khi[off]     = h0;  Klo[off]     = f2bf(r0 - bf2f(h0));
    Khi[off + 1] = h1;  Klo[off + 1] = f2bf(r1 - bf2f(h1));
}

// ---------------------------------------------------------------------------
// RoPE for V fused with transpose (unchanged): V2d -> Vt bf16 (B,NKV,HD,T)
// ---------------------------------------------------------------------------
__global__ __launch_bounds__(256)
void rope_v_t(const float* __restrict__ V2d, short* __restrict__ Vt)
{
    __shared__ short Ls[128][40];
    const int g  = blockIdx.x;
    const int kh = blockIdx.y;
    const int bb = blockIdx.z;
    const int t  = threadIdx.x;

    const float* src = V2d + ((size_t)bb * Tc + (kh << 9) + (g << 3)) * KVEc;
    #pragma unroll
    for (int i = 0; i < 4; ++i) {
        int e = i * 256 + t;
        float4 v = ((const float4*)src)[e];
        int row = e >> 7;
        int col = (e & 127) << 2;
        int tkl = (row << 2) + (col >> 7);
        int d0  = col & 127;
        int tk  = (g << 5) + tkl;
        float fv[4] = {v.x, v.y, v.z, v.w};
        #pragma unroll
        for (int p = 0; p < 2; ++p) {
            int j = (d0 >> 1) + p;
            float theta = powf(10000.0f, -(float)j * (1.0f / 64.0f));
            float ang = (float)tk * theta;
            float s, c;
            sincosf(ang, &s, &c);
            float a = fv[2 * p], b = fv[2 * p + 1];
            Ls[d0 + 2 * p    ][tkl] = f2bf(a * c - b * s);
            Ls[d0 + 2 * p + 1][tkl] = f2bf(a * s + b * c);
        }
    }
    __syncthreads();
    const int d = t >> 1;
    const int h16 = (t & 1) << 4;
    short* dst = Vt + (((size_t)bb * NKVc + kh) * HDc + d) * Tc + (g << 5) + h16;
    bf16x8 o0 = *(const bf16x8*)&Ls[d][h16];
    bf16x8 o1 = *(const bf16x8*)&Ls[d][h16 + 8];
    *(bf16x8*)dst = o0;
    *(bf16x8*)(dst + 8) = o1;
}

// ---------------------------------------------------------------------------
// Softmax + P->A-fragment for one 16-q subtile (macro: keeps all indexing
// compile-time-static; rule #20).  Uses kernel-scope: quad, l16, srcA, srcB,
// q1v, SCALE2, MASKED2, ex2.  S is f32x4[4] (clobbered), MR/LPV scalars,
// OACC f32x4[8], MW u64 mask word, AK0/AK1 output unions (keys 0-31/32-63).
// ---------------------------------------------------------------------------
#define SM_AND_P(S, MR, LPV, OACC, MW, AK0, AK1)                               \
  do {                                                                         \
    const unsigned mlo_ = (unsigned)(MW);                                      \
    const unsigned mhi_ = (unsigned)((MW) >> 32);                              \
    const int gq_ = quad << 2;                                                 \
    const unsigned fm_0 = mlo_ >> gq_, fm_1 = (mlo_ >> 16) >> gq_;             \
    const unsigned fm_2 = mhi_ >> gq_, fm_3 = (mhi_ >> 16) >> gq_;             \
    _Pragma("unroll")                                                          \
    for (int r_ = 0; r_ < 4; ++r_) {                                           \
      S[0][r_] = (fm_0 & (1u << r_)) ? S[0][r_] * SCALE2 : MASKED2;            \
      S[1][r_] = (fm_1 & (1u << r_)) ? S[1][r_] * SCALE2 : MASKED2;            \
      S[2][r_] = (fm_2 & (1u << r_)) ? S[2][r_] * SCALE2 : MASKED2;            \
      S[3][r_] = (fm_3 & (1u << r_)) ? S[3][r_] * SCALE2 : MASKED2;            \
    }                                                                          \
    float mt_;                                                                 \
    {                                                                          \
      float a0_ = fmaxf(fmaxf(S[0][0], S[0][1]), fmaxf(S[0][2], S[0][3]));     \
      float a1_ = fmaxf(fmaxf(S[1][0], S[1][1]), fmaxf(S[1][2], S[1][3]));     \
      float a2_ = fmaxf(fmaxf(S[2][0], S[2][1]), fmaxf(S[2][2], S[2][3]));     \
      float a3_ = fmaxf(fmaxf(S[3][0], S[3][1]), fmaxf(S[3][2], S[3][3]));     \
      mt_ = fmaxf(fmaxf(a0_, a1_), fmaxf(a2_, a3_));                           \
    }                                                                          \
    mt_ = fmaxf(mt_, __shfl_xor(mt_, 16));                                     \
    mt_ = fmaxf(mt_, __shfl_xor(mt_, 32));                                     \
    const bool res_ = (mt_ > (MR) + 8.0f);                                     \
    if (__any(res_)) {                                                         \
      const float mn_ = res_ ? mt_ : (MR);                                     \
      const float alq_ = ex2((MR) - mn_);                                      \
      MR = mn_;                                                                \
      LPV *= alq_;                                                             \
      float alo_0 = __shfl(alq_, quad * 20 + 0);                               \
      float alo_1 = __shfl(alq_, quad * 20 + 1);                               \
      float alo_2 = __shfl(alq_, quad * 20 + 2);                               \
      float alo_3 = __shfl(alq_, quad * 20 + 3);                               \
      _Pragma("unroll")                                                        \
      for (int nc_ = 0; nc_ < 8; ++nc_) {                                      \
        OACC[nc_][0] *= alo_0; OACC[nc_][1] *= alo_1;                          \
        OACC[nc_][2] *= alo_2; OACC[nc_][3] *= alo_3;                          \
      }                                                                        \
    }                                                                          \
    {                                                                          \
      float t0_ = 0.f, t1_ = 0.f;                                              \
      _Pragma("unroll")                                                        \
      for (int nt_ = 0; nt_ < 4; ++nt_) {                                      \
        float p0_ = ex2(S[nt_][0] - (MR));                                     \
        float p1_ = ex2(S[nt_][1] - (MR));                                     \
        float p2_ = ex2(S[nt_][2] - (MR));                                     \
        float p3_ = ex2(S[nt_][3] - (MR));                                     \
        S[nt_][0] = p0_; S[nt_][1] = p1_;                                      \
        S[nt_][2] = p2_; S[nt_][3] = p3_;                                      \
        t0_ += p0_ + p1_; t1_ += p2_ + p3_;                                    \
      }                                                                        \
      LPV += t0_ + t1_;                                                        \
    }                                                                          \
    int pk00_, pk01_, pk10_, pk11_, pk20_, pk21_, pk30_, pk31_;                \
    asm("v_cvt_pk_bf16_f32 %0, %1, %2" : "=v"(pk00_) : "v"(S[0][0]), "v"(S[0][1])); \
    asm("v_cvt_pk_bf16_f32 %0, %1, %2" : "=v"(pk01_) : "v"(S[0][2]), "v"(S[0][3])); \
    asm("v_cvt_pk_bf16_f32 %0, %1, %2" : "=v"(pk10_) : "v"(S[1][0]), "v"(S[1][1])); \
    asm("v_cvt_pk_bf16_f32 %0, %1, %2" : "=v"(pk11_) : "v"(S[1][2]), "v"(S[1][3])); \
    asm("v_cvt_pk_bf16_f32 %0, %1, %2" : "=v"(pk20_) : "v"(S[2][0]), "v"(S[2][1])); \
    asm("v_cvt_pk_bf16_f32 %0, %1, %2" : "=v"(pk21_) : "v"(S[2][2]), "v"(S[2][3])); \
    asm("v_cvt_pk_bf16_f32 %0, %1, %2" : "=v"(pk30_) : "v"(S[3][0]), "v"(S[3][1])); \
    asm("v_cvt_pk_bf16_f32 %0, %1, %2" : "=v"(pk31_) : "v"(S[3][2]), "v"(S[3][3])); \
    {                                                                          \
      int u0_, u1_;                                                            \
      u0_ = __shfl(pk00_, srcA); u1_ = __shfl(pk10_, srcA); AK0.d[0] = q1v ? u1_ : u0_; \
      u0_ = __shfl(pk01_, srcA); u1_ = __shfl(pk11_, srcA); AK0.d[1] = q1v ? u1_ : u0_; \
      u0_ = __shfl(pk00_, srcB); u1_ = __shfl(pk10_, srcB); AK0.d[2] = q1v ? u1_ : u0_; \
      u0_ = __shfl(pk01_, srcB); u1_ = __shfl(pk11_, srcB); AK0.d[3] = q1v ? u1_ : u0_; \
      u0_ = __shfl(pk20_, srcA); u1_ = __shfl(pk30_, srcA); AK1.d[0] = q1v ? u1_ : u0_; \
      u0_ = __shfl(pk21_, srcA); u1_ = __shfl(pk31_, srcA); AK1.d[1] = q1v ? u1_ : u0_; \
      u0_ = __shfl(pk20_, srcB); u1_ = __shfl(pk30_, srcB); AK1.d[2] = q1v ? u1_ : u0_; \
      u0_ = __shfl(pk21_, srcB); u1_ = __shfl(pk31_, srcB); AK1.d[3] = q1v ? u1_ : u0_; \
    }                                                                          \
  } while (0)

// ---------------------------------------------------------------------------
// MFMA flash attention — R8: R7 (32 q/wave, two 16-q subtiles, shared K/V
// fragment reads) + occupancy push to 3 blocks/CU (12 waves): Q loaded as
// pre-split bf16 (from QOUT GEMM epilogue — no fp32 temps), mask words
// loaded in-loop (no cross-phase liveness), __launch_bounds__(256,3).
// vmcnt ledger: A-wait vmcnt(4) [K(t)x8 oldest, V(t)x4 remain]; mask x2
// issued after A; pre-softmax vmcnt(8) drains V+mask, leaves K(t+1)x8.
// ---------------------------------------------------------------------------
__global__ __launch_bounds__(256, 3)
void attn_mfma(const short* __restrict__ Qhi_g, const short* __restrict__ Qlo_g,
               const short* __restrict__ Khi_g, const short* __restrict__ Klo_g,
               const short* __restrict__ Vt_g,
               const unsigned long long* __restrict__ Mb, short* __restrict__ AObf)
{
    __shared__ short KhiS[64 * 128];
    __shared__ short KloS[64 * 128];
    __shared__ short VtS [128 * 64];

    // XCD-aware swizzle: all 16 q-blocks of one (b,h) group land on the same
    // XCD (fid%8), so its K/V (1.5 MB) stays resident in that XCD's 4 MB L2.
    const int fid  = blockIdx.x + 16 * (blockIdx.y + 16 * blockIdx.z);
    const int slot = fid >> 3;                       // 0..127
    const int grp  = (fid & 7) + 8 * (slot >> 4);    // 0..63 = (b,h)
    const int qb   = slot & 15;                      // 0..15 (128-q block)
    const int h    = grp & 15;
    const int bb   = grp >> 4;

    const int t    = threadIdx.x;
    const int w    = t >> 6;     // wave 0..3
    const int L    = t & 63;
    const int l16  = L & 15;
    const int quad = L >> 4;
    const int q1v  = quad >> 1;
    const int kh   = h & (NKVc - 1);     // jnp.tile: head h -> kv-head h%4
    const int tq0  = qb * 128 + w * 16;          // subtile 0 q-base
    const int tq1  = tq0 + 64;                   // subtile 1 q-base

    // ---- Q fragments for both subtiles: direct bf16 hi/lo vector loads ----
    bf16x8 qhi0[4], qlo0[4], qhi1[4], qlo1[4];
    {
        const size_t qoff = (size_t)(bb * Tc + h * HDc + qb * 8 + w) * Ec
                          + 128 * l16 + quad * 8;
        const short* qh = Qhi_g + qoff;
        const short* ql = Qlo_g + qoff;
        #pragma unroll
        for (int kc = 0; kc < 4; ++kc) {
            qhi0[kc] = *(const bf16x8*)(qh + kc * 32);
            qlo0[kc] = *(const bf16x8*)(ql + kc * 32);
            qhi1[kc] = *(const bf16x8*)(qh + (size_t)4 * Ec + kc * 32);
            qlo1[kc] = *(const bf16x8*)(ql + (size_t)4 * Ec + kc * 32);
        }
    }

    // per-lane online-softmax state (subtile 0 and 1)
    float m0 = -INFINITY, lp0 = 0.0f;
    float m1 = -INFINITY, lp1 = 0.0f;
    f32x4 o0[8], o1[8];
    #pragma unroll
    for (int nc = 0; nc < 8; ++nc) {
        o0[nc] = (f32x4){0, 0, 0, 0};
        o1[nc] = (f32x4){0, 0, 0, 0};
    }

    const short* kbh = Khi_g + ((size_t)(bb * NKVc + kh)) * Tc * HDc;
    const short* kbl = Klo_g + ((size_t)(bb * NKVc + kh)) * Tc * HDc;
    const short* vb  = Vt_g  + ((size_t)(bb * NKVc + kh)) * HDc * Tc;
    const unsigned long long* mrow0 =
        Mb + ((size_t)(bb * Tc + tq0 + l16)) * (Tc / 64);
    const unsigned long long* mrow1 = mrow0 + (size_t)64 * (Tc / 64);

    constexpr float SCALE2  = 11.313708498984761f * 1.4426950408889634f;
    constexpr float MASKED2 = 1e-9f * 1.4426950408889634f;

    // staging lane decode
    const int km   = L >> 4;
    const int kpos = L & 15;
    const int vm   = L >> 3;
    const int vc   = ((L & 7) - vm) & 7;

    // shuffle source lanes for P redistribution (same l16, quad remap)
    const int srcA = l16 + 16 * ((2 * quad)     & 3);
    const int srcB = l16 + 16 * ((2 * quad + 1) & 3);

    // 8 vmcnt events per call, wave w stages wl = 4w..4w+3
    auto stageK = [&](int kt) {
        #pragma unroll
        for (int i = 0; i < 4; ++i) {
            const int wl = w * 4 + i;
            const int krow = wl * 4 + km;
            const int kc_ = (kpos - (krow & 15)) & 15;
            const size_t go = (size_t)(kt * 64 + krow) * HDc + kc_ * 8;
            gload16(kbh + go, &KhiS[wl * 512]);
            gload16(kbl + go, &KloS[wl * 512]);
        }
    };
    // 4 vmcnt events per call
    auto stageV = [&](int kt) {
        #pragma unroll
        for (int i = 0; i < 4; ++i) {
            const int wl = w * 4 + i;
            const int vrow = wl * 8 + vm;
            gload16(vb + (size_t)vrow * Tc + kt * 64 + vc * 8, &VtS[wl * 512]);
        }
    };

    // ---- prologue: drain Q loads so staging vmcnt arithmetic is exact ----
    asm volatile("s_waitcnt vmcnt(0)" ::: "memory");
    __builtin_amdgcn_sched_barrier(0);
    stageK(0);
    __builtin_amdgcn_sched_barrier(0);
    stageV(0);
    __builtin_amdgcn_sched_barrier(0);

    union U { int d[4]; bf16x8 v; };

    for (int kt = 0; kt < Tc / 64; ++kt) {
        const int ktn = (kt + 1) & 31;   // wrap: tile-0 re-stage is harmless

        // A: own K(t) landed (leaves V x4 in flight), then all-waves sync
        asm volatile("s_waitcnt vmcnt(4)" ::: "memory");
        __builtin_amdgcn_s_barrier();
        __builtin_amdgcn_sched_barrier(0);

        // mask words for THIS tile — land under QK^T (L2-hot: shared by all
        // 16 heads of the same (b,q) rows)
        const unsigned long long mw0 = mrow0[kt];
        const unsigned long long mw1 = mrow1[kt];

        // ---- swapped QK^T for BOTH subtiles, K-fragments read once ----
        f32x4 s0[4], s1[4];
        #pragma unroll
        for (int nt = 0; nt < 4; ++nt) {
            f32x4 a0 = (f32x4){0, 0, 0, 0};
            f32x4 a1 = (f32x4){0, 0, 0, 0};
            #pragma unroll
            for (int kc = 0; kc < 4; ++kc) {
                const int ch = (((nt * 4 + (l16 >> 2)) << 6) + ((l16 & 3) << 4)
                                + ((kc * 4 + quad + l16) & 15)) << 3;
                bf16x8 khiF = *(const bf16x8*)&KhiS[ch];
                bf16x8 kloF = *(const bf16x8*)&KloS[ch];
                a0 = __builtin_amdgcn_mfma_f32_16x16x32_bf16(khiF, qhi0[kc], a0, 0, 0, 0);
                a0 = __builtin_amdgcn_mfma_f32_16x16x32_bf16(khiF, qlo0[kc], a0, 0, 0, 0);
                a0 = __builtin_amdgcn_mfma_f32_16x16x32_bf16(kloF, qhi0[kc], a0, 0, 0, 0);
                a1 = __builtin_amdgcn_mfma_f32_16x16x32_bf16(khiF, qhi1[kc], a1, 0, 0, 0);
                a1 = __builtin_amdgcn_mfma_f32_16x16x32_bf16(khiF, qlo1[kc], a1, 0, 0, 0);
                a1 = __builtin_amdgcn_mfma_f32_16x16x32_bf16(kloF, qhi1[kc], a1, 0, 0, 0);
            }
            s0[nt] = a0;
            s1[nt] = a1;
        }

        // E: all waves done reading K buffers -> safe to overwrite
        asm volatile("s_waitcnt lgkmcnt(0)" ::: "memory");
        __builtin_amdgcn_sched_barrier(0);
        __builtin_amdgcn_s_barrier();
        __builtin_amdgcn_sched_barrier(0);
        // F: prefetch next K (flies under softmax + PV)
        stageK(ktn);
        __builtin_amdgcn_sched_barrier(0);

        // drain own V(t) + mask (oldest 6); K(t+1) x8 stay in flight
        asm volatile("s_waitcnt vmcnt(8)" ::: "memory");

        // ---- softmax + P->A-fragments, per subtile ----
        U A00, A01, A10, A11;
        SM_AND_P(s0, m0, lp0, o0, mw0, A00, A01);
        SM_AND_P(s1, m1, lp1, o1, mw1, A10, A11);

        // H: all waves have drained their V loads (vmcnt(8) above) -> sync
        __builtin_amdgcn_s_barrier();
        __builtin_amdgcn_sched_barrier(0);

        // ---- PV for BOTH subtiles, V-fragments read once ----
        #pragma unroll
        for (int nc = 0; nc < 8; ++nc) {
            const int rg = (nc * 2 + (l16 >> 3)) << 6;
            const int rm = l16 & 7;
            const int ch0 = (rg + (rm << 3) + ((quad + rm) & 7)) << 3;
            const int ch1 = (rg + (rm << 3) + ((quad + 4 + rm) & 7)) << 3;
            bf16x8 b0 = *(const bf16x8*)&VtS[ch0];
            bf16x8 b1 = *(const bf16x8*)&VtS[ch1];
            o0[nc] = __builtin_amdgcn_mfma_f32_16x16x32_bf16(A00.v, b0, o0[nc], 0, 0, 0);
            o0[nc] = __builtin_amdgcn_mfma_f32_16x16x32_bf16(A01.v, b1, o0[nc], 0, 0, 0);
            o1[nc] = __builtin_amdgcn_mfma_f32_16x16x32_bf16(A10.v, b0, o1[nc], 0, 0, 0);
            o1[nc] = __builtin_amdgcn_mfma_f32_16x16x32_bf16(A11.v, b1, o1[nc], 0, 0, 0);
        }

        // K: all waves done reading VtS -> safe to overwrite
        asm volatile("s_waitcnt lgkmcnt(0)" ::: "memory");
        __builtin_amdgcn_sched_barrier(0);
        __builtin_amdgcn_s_barrier();
        __builtin_amdgcn_sched_barrier(0);
        // L: prefetch next V (flies under next QK^T)
        stageV(ktn);
        __builtin_amdgcn_sched_barrier(0);
    }

    // drain outstanding prefetch DMA before the block can retire
    asm volatile("s_waitcnt vmcnt(0)" ::: "memory");

    // ---- final l reduction across quads, then write both subtiles ----
    lp0 += __shfl_xor(lp0, 16);
    lp0 += __shfl_xor(lp0, 32);
    lp1 += __shfl_xor(lp1, 16);
    lp1 += __shfl_xor(lp1, 32);
    const float invl0 = 1.0f / lp0;
    const float invl1 = 1.0f / lp1;
    float invo0[4], invo1[4];
    #pragma unroll
    for (int r = 0; r < 4; ++r) {
        invo0[r] = __shfl(invl0, quad * 16 + quad * 4 + r);
        invo1[r] = __shfl(invl1, quad * 16 + quad * 4 + r);
    }

    #pragma unroll
    for (int r = 0; r < 4; ++r) {
        short* orow = AObf + ((size_t)(bb * Tc + tq0 + quad * 4 + r)) * Ec
                           + h * HDc + l16;
        #pragma unroll
        for (int nc = 0; nc < 8; ++nc)
            orow[nc * 16] = f2bf(o0[nc][r] * invo0[r]);
    }
    #pragma unroll
    for (int r = 0; r < 4; ++r) {
        short* orow = AObf + ((size_t)(bb * Tc + tq1 + quad * 4 + r)) * Ec
                           + h * HDc + l16;
        #pragma unroll
        for (int nc = 0; nc < 8; ++nc)
            orow[nc * 16] = f2bf(o1[nc][r] * invo1[r]);
    }
}

// ---------------------------------------------------------------------------
// Launch
// ---------------------------------------------------------------------------
extern "C" void kernel_launch(void* const* d_in, const int* in_sizes, int n_in,
                              void* d_out, int out_size, void* d_ws, size_t ws_size,
                              hipStream_t stream)
{
    const float* x    = (const float*)d_in[0];
    const int*  amask = (const int*)  d_in[1];
    const float* Wq   = (const float*)d_in[2];
    const float* bq   = (const float*)d_in[3];
    const float* Wk   = (const float*)d_in[4];
    const float* bk   = (const float*)d_in[5];
    const float* Wv   = (const float*)d_in[6];
    const float* bv   = (const float*)d_in[7];
    const float* Wo   = (const float*)d_in[8];
    const float* bo   = (const float*)d_in[9];
    float* out = (float*)d_out;

    // Workspace layout (bytes), 160 MiB + 2 MiB bitmask:
    //  [0,   32M)  Qhi bf16   [32M,64M) Qlo bf16  (Q-GEMM split epilogue)
    //  [64M, 96M)  Xhi bf16            -> AObf bf16 (after V-GEMM)
    //  [96M,128M)  Xlo bf16            -> V2d fp32 [96M,112M) + Khi/Klo [112M,128M)
    //  [128M,144M) WqT hi+lo           -> WkT hi/lo + WvT + WoT (after Q-GEMM)
    //  [144M,160M) K2d fp32            -> Vt bf16 (after rope_k)
    //  [160M,162M) Mbits u64
    char* ws = (char*)d_ws;
    short* Qhi   = (short*)(ws);
    short* Qlo   = (short*)(ws + 33554432);
    short* Xhi   = (short*)(ws + 67108864);
    short* Xlo   = (short*)(ws + 100663296);
    short* WqThi = (short*)(ws + 134217728);
    short* WqTlo = (short*)(ws + 134217728 + 8388608);
    float* K2d   = (float*)(ws + 150994944);
    // overlays:
    float* V2d   = (float*)(ws + 100663296);              // over Xlo[0:16M)
    short* Khi   = (short*)(ws + 100663296 + 16777216);   // over Xlo[16M:24M)
    short* Klo   = (short*)(ws + 100663296 + 25165824);   // over Xlo[24M:32M)
    short* WkThi = (short*)(ws + 134217728);              // over WqT after Q-GEMM
    short* WkTlo = (short*)(ws + 134217728 + 2097152);
    short* WvThi = (short*)(ws + 134217728 + 4194304);
    short* WoThi = (short*)(ws + 134217728 + 8388608);
    short* Vt    = (short*)(ws + 150994944);              // over K2d after rope_k
    short* AObf  = (short*)(ws + 67108864);               // over Xhi after V-GEMM
    unsigned long long* Mb = (unsigned long long*)(ws + 167772160);

    const int M = Bc * Tc;      // 8192
    dim3 blk(256);

    // 0) mask -> bitmask (B*T*T/64 = 262144 words, 4 words/block)
    mask_bits<<<(Bc * Tc * (Tc / 64)) / 4, blk, 0, stream>>>(amask, Mb);
    // 1) Wq^T split, x split
    transpose_split<<<dim3(Ec / 32, Ec / 32), blk, 0, stream>>>(Wq, WqThi, WqTlo, Ec, Ec);
    convert_split<<<(M * Ec / 4) / 256, blk, 0, stream>>>(x, Xhi, Xlo);
    // 2) Q projection (split, fp32-fidelity, bf16 hi/lo output)
    gemm_mfma<true, true><<<dim3(M / 128, Ec / 128), blk, 0, stream>>>(
        Xhi, Xlo, WqThi, WqTlo, bq, nullptr, Qhi, Qlo, M, Ec, Ec);
    // 3) remaining weight transposes (into the now-dead WqT slab)
    transpose_split<<<dim3(Ec / 32, KVEc / 32), blk, 0, stream>>>(Wk, WkThi, WkTlo, Ec, KVEc);
    transpose_split<<<dim3(Ec / 32, KVEc / 32), blk, 0, stream>>>(Wv, WvThi, nullptr, Ec, KVEc);
    transpose_split<<<dim3(Ec / 32, Ec / 32), blk, 0, stream>>>(Wo, WoThi, nullptr, Ec, Ec);
    // 4) K projection (split), V projection (plain)
    gemm_mfma<true, false><<<dim3(M / 128, KVEc / 128), blk, 0, stream>>>(
        Xhi, Xlo, WkThi, WkTlo, bk, K2d, nullptr, nullptr, M, KVEc, Ec);
    gemm_mfma<false, false><<<dim3(M / 128, KVEc / 128), blk, 0, stream>>>(
        Xhi, nullptr, WvThi, nullptr, bv, V2d, nullptr, nullptr, M, KVEc, Ec);
    // 5) RoPE: K -> hi/lo bf16, V -> transposed bf16
    rope_k<<<(Bc * NKVc * Tc * 64) / 256, blk, 0, stream>>>(K2d, Khi, Klo);
    rope_v_t<<<dim3(Tc / 32, NKVc, Bc), blk, 0, stream>>>(V2d, Vt);
    // 6) attention (256 threads, 128 q-rows/block, 32 q/wave) -> bf16 AO
    attn_mfma<<<dim3(Tc / 128, NHc, Bc), blk, 0, stream>>>(
        Qhi, Qlo, Khi, Klo, Vt, Mb, AObf);
    // 7) output projection (plain)
    gemm_mfma<false, false><<<dim3(M / 128, Ec / 128), blk, 0, stream>>>(
        AObf, nullptr, WoThi, nullptr, bo, out, nullptr, nullptr, M, Ec, Ec);
}

// Round 6
// 1048.863 us; speedup vs baseline: 1.8771x; 1.8771x over previous
//
#include <hip/hip_runtime.h>
#include <math.h>

// Problem constants (B,T,E)=(4,2048,2048), NH=16, NKV=4, HD=128
constexpr int Bc   = 4;
constexpr int Tc   = 2048;
constexpr int Ec   = 2048;
constexpr int NHc  = 16;
constexpr int NKVc = 4;
constexpr int HDc  = 128;
constexpr int KVEc = NKVc * HDc; // 512

typedef __attribute__((ext_vector_type(8))) short bf16x8;
typedef __attribute__((ext_vector_type(4))) short short4v;
typedef __attribute__((ext_vector_type(4))) float f32x4;

__device__ __forceinline__ short f2bf(float f) {   // round-to-nearest-even
    union { float f; unsigned u; } v; v.f = f;
    unsigned r = v.u + 0x7FFF + ((v.u >> 16) & 1);
    return (short)(r >> 16);
}
__device__ __forceinline__ float bf2f(short s) {
    union { unsigned u; float f; } v; v.u = ((unsigned)(unsigned short)s) << 16;
    return v.f;
}
// 2^x via the hardware transcendental (v_exp_f32 computes 2^x).
// __exp2f collides with glibc math.h on this toolchain; inline asm is the
// guaranteed-single-instruction spelling.
__device__ __forceinline__ float ex2(float x) {
    float r; asm("v_exp_f32 %0, %1" : "=v"(r) : "v"(x)); return r;
}
// async global->LDS, 16B per lane; LDS dest = wave-uniform base + lane*16
__device__ __forceinline__ void gload16(const void* g, void* l) {
    __builtin_amdgcn_global_load_lds(
        (const __attribute__((address_space(1))) unsigned*)g,
        (__attribute__((address_space(3))) unsigned*)l, 16, 0, 0);
}

// ---------------------------------------------------------------------------
// Prep: x fp32 -> hi/lo bf16 (same layout)
// ---------------------------------------------------------------------------
__global__ __launch_bounds__(256)
void convert_split(const float* __restrict__ X, short* __restrict__ Xhi,
                   short* __restrict__ Xlo)
{
    int i = blockIdx.x * 256 + threadIdx.x;    // float4 index
    float4 v = ((const float4*)X)[i];
    float fv[4] = {v.x, v.y, v.z, v.w};
    short4v hi, lo;
    #pragma unroll
    for (int j = 0; j < 4; ++j) {
        hi[j] = f2bf(fv[j]);
        lo[j] = f2bf(fv[j] - bf2f(hi[j]));
    }
    ((short4v*)Xhi)[i] = hi;
    ((short4v*)Xlo)[i] = lo;
}

// ---------------------------------------------------------------------------
// Prep: W [K][N] fp32 -> WT hi (and optional lo) [N][K] bf16
// ---------------------------------------------------------------------------
__global__ __launch_bounds__(256)
void transpose_split(const float* __restrict__ W, short* __restrict__ WThi,
                     short* __restrict__ WTlo, int K, int N)
{
    __shared__ float Ls[32][33];
    const int k0 = blockIdx.x * 32, n0 = blockIdx.y * 32;
    const int t = threadIdx.x;
    const int r = t >> 3, c4 = (t & 7) << 2;
    float4 v = *(const float4*)(W + (size_t)(k0 + r) * N + n0 + c4);
    Ls[r][c4 + 0] = v.x; Ls[r][c4 + 1] = v.y;
    Ls[r][c4 + 2] = v.z; Ls[r][c4 + 3] = v.w;
    __syncthreads();
    short4v hi, lo;
    #pragma unroll
    for (int i = 0; i < 4; ++i) {
        float f = Ls[c4 + i][r];
        hi[i] = f2bf(f);
        lo[i] = f2bf(f - bf2f(hi[i]));
    }
    *(short4v*)(WThi + (size_t)(n0 + r) * K + k0 + c4) = hi;
    if (WTlo) *(short4v*)(WTlo + (size_t)(n0 + r) * K + k0 + c4) = lo;
}

// ---------------------------------------------------------------------------
// Mask -> bitmask: Mb[b][q][w] bit j = (mask[b][q][w*64+j] != 0)
// ---------------------------------------------------------------------------
__global__ __launch_bounds__(256)
void mask_bits(const int* __restrict__ mask, unsigned long long* __restrict__ Mb)
{
    const int widx = blockIdx.x * 4 + (threadIdx.x >> 6);
    const int L = threadIdx.x & 63;
    const int m = mask[(size_t)widx * 64 + L];
    unsigned long long bits = __ballot(m != 0);
    if (L == 0) Mb[widx] = bits;
}

// ---------------------------------------------------------------------------
// MFMA GEMM: C = A @ B^T + bias, 128x128 tile, BK=32.
// QOUT: epilogue writes split bf16 (Chi/Clo) instead of fp32 C — used for
// the Q projection, whose only consumer (attn) wants bf16 hi/lo fragments.
// ---------------------------------------------------------------------------
template <bool SPLIT, bool QOUT>
__global__ __launch_bounds__(256, 2)
void gemm_mfma(const short* __restrict__ Ahi, const short* __restrict__ Alo,
               const short* __restrict__ Bhi, const short* __restrict__ Blo,
               const float* __restrict__ bias, float* __restrict__ C,
               short* __restrict__ Chi, short* __restrict__ Clo,
               int M, int N, int K)
{
    __shared__ short AsH[128 * 32];
    __shared__ short BsH[128 * 32];
    __shared__ short AsL[SPLIT ? 128 * 32 : 8];
    __shared__ short BsL[SPLIT ? 128 * 32 : 8];

    const int t = threadIdx.x;
    const int w = t >> 6, L = t & 63;
    const int l16 = L & 15, quad = L >> 4;
    const int wr = w >> 1, wc = w & 1;
    const int bm = blockIdx.x * 128, bn = blockIdx.y * 128;

    const int sm = L >> 2;
    const int sq = ((L & 3) - (sm >> 2)) & 3;
    const int scol = sq * 8;

    f32x4 acc[4][4];
    #pragma unroll
    for (int mi = 0; mi < 4; ++mi)
        #pragma unroll
        for (int ni = 0; ni < 4; ++ni) acc[mi][ni] = (f32x4){0, 0, 0, 0};

    const int fxor = (quad + (l16 >> 2)) & 3;

    for (int k0 = 0; k0 < K; k0 += 32) {
        __syncthreads();
        #pragma unroll
        for (int i = 0; i < 2; ++i) {
            const int wl = w * 2 + i;
            const size_t ra = (size_t)(bm + wl * 16 + sm) * K + k0 + scol;
            const size_t rb = (size_t)(bn + wl * 16 + sm) * K + k0 + scol;
            gload16(Ahi + ra, &AsH[wl * 512]);
            gload16(Bhi + rb, &BsH[wl * 512]);
            if (SPLIT) {
                gload16(Alo + ra, &AsL[wl * 512]);
                gload16(Blo + rb, &BsL[wl * 512]);
            }
        }
        __syncthreads();

        bf16x8 ah[4], bh[4], al[4], bl[4];
        #pragma unroll
        for (int mi = 0; mi < 4; ++mi) {
            const int ch = ((wr * 4 + mi) * 64 + l16 * 4 + fxor) * 8;
            ah[mi] = *(const bf16x8*)&AsH[ch];
            if (SPLIT) al[mi] = *(const bf16x8*)&AsL[ch];
        }
        #pragma unroll
        for (int ni = 0; ni < 4; ++ni) {
            const int ch = ((wc * 4 + ni) * 64 + l16 * 4 + fxor) * 8;
            bh[ni] = *(const bf16x8*)&BsH[ch];
            if (SPLIT) bl[ni] = *(const bf16x8*)&BsL[ch];
        }
        #pragma unroll
        for (int mi = 0; mi < 4; ++mi)
            #pragma unroll
            for (int ni = 0; ni < 4; ++ni) {
                acc[mi][ni] = __builtin_amdgcn_mfma_f32_16x16x32_bf16(
                    ah[mi], bh[ni], acc[mi][ni], 0, 0, 0);
                if (SPLIT) {
                    acc[mi][ni] = __builtin_amdgcn_mfma_f32_16x16x32_bf16(
                        al[mi], bh[ni], acc[mi][ni], 0, 0, 0);
                    acc[mi][ni] = __builtin_amdgcn_mfma_f32_16x16x32_bf16(
                        ah[mi], bl[ni], acc[mi][ni], 0, 0, 0);
                }
            }
    }

    #pragma unroll
    for (int ni = 0; ni < 4; ++ni) {
        const int col = bn + wc * 64 + ni * 16 + l16;
        const float bv = bias[col];
        #pragma unroll
        for (int mi = 0; mi < 4; ++mi) {
            #pragma unroll
            for (int r = 0; r < 4; ++r) {
                const int row = bm + wr * 64 + mi * 16 + quad * 4 + r;
                const float f = acc[mi][ni][r] + bv;
                if (QOUT) {
                    const short hi = f2bf(f);
                    Chi[(size_t)row * N + col] = hi;
                    Clo[(size_t)row * N + col] = f2bf(f - bf2f(hi));
                } else {
                    C[(size_t)row * N + col] = f;
                }
            }
        }
    }
}

// ---------------------------------------------------------------------------
// RoPE for K: fp32 K2d (B,T,512) -> Khi/Klo bf16 (B,NKV,T,HD)  (unchanged)
// ---------------------------------------------------------------------------
__global__ __launch_bounds__(256)
void rope_k(const float* __restrict__ X2d, short* __restrict__ Khi,
            short* __restrict__ Klo)
{
    const int idx = blockIdx.x * 256 + threadIdx.x;
    const int j  = idx & 63;
    const int tk = (idx >> 6) & (Tc - 1);
    const int kh = (idx >> 17) & (NKVc - 1);
    const int bb = idx >> 19;
    const int row = (kh << 9) + (tk >> 2);
    const int col = ((tk & 3) << 7) + (j << 1);
    const float* src = X2d + ((size_t)bb * Tc + row) * KVEc + col;
    const float a = src[0];
    const float b = src[1];
    const float theta = powf(10000.0f, -(float)j * (1.0f / 64.0f));
    const float ang = (float)tk * theta;
    float s, c;
    sincosf(ang, &s, &c);
    const float r0 = a * c - b * s;
    const float r1 = a * s + b * c;
    const size_t off = (((size_t)bb * NKVc + kh) * Tc + tk) * HDc + (j << 1);
    short h0 = f2bf(r0), h1 = f2bf(r1);
    Khi[off]     = h0;  Klo[off]     = f2bf(r0 - bf2f(h0));
    Khi[off + 1] = h1;  Klo[off + 1] = f2bf(r1 - bf2f(h1));
}

// ---------------------------------------------------------------------------
// RoPE for V fused with transpose (unchanged): V2d -> Vt bf16 (B,NKV,HD,T)
// ---------------------------------------------------------------------------
__global__ __launch_bounds__(256)
void rope_v_t(const float* __restrict__ V2d, short* __restrict__ Vt)
{
    __shared__ short Ls[128][40];
    const int g  = blockIdx.x;
    const int kh = blockIdx.y;
    const int bb = blockIdx.z;
    const int t  = threadIdx.x;

    const float* src = V2d + ((size_t)bb * Tc + (kh << 9) + (g << 3)) * KVEc;
    #pragma unroll
    for (int i = 0; i < 4; ++i) {
        int e = i * 256 + t;
        float4 v = ((const float4*)src)[e];
        int row = e >> 7;
        int col = (e & 127) << 2;
        int tkl = (row << 2) + (col >> 7);
        int d0  = col & 127;
        int tk  = (g << 5) + tkl;
        float fv[4] = {v.x, v.y, v.z, v.w};
        #pragma unroll
        for (int p = 0; p < 2; ++p) {
            int j = (d0 >> 1) + p;
            float theta = powf(10000.0f, -(float)j * (1.0f / 64.0f));
            float ang = (float)tk * theta;
            float s, c;
            sincosf(ang, &s, &c);
            float a = fv[2 * p], b = fv[2 * p + 1];
            Ls[d0 + 2 * p    ][tkl] = f2bf(a * c - b * s);
            Ls[d0 + 2 * p + 1][tkl] = f2bf(a * s + b * c);
        }
    }
    __syncthreads();
    const int d = t >> 1;
    const int h16 = (t & 1) << 4;
    short* dst = Vt + (((size_t)bb * NKVc + kh) * HDc + d) * Tc + (g << 5) + h16;
    bf16x8 o0 = *(const bf16x8*)&Ls[d][h16];
    bf16x8 o1 = *(const bf16x8*)&Ls[d][h16 + 8];
    *(bf16x8*)dst = o0;
    *(bf16x8*)(dst + 8) = o1;
}

// ---------------------------------------------------------------------------
// Softmax + P->A-fragment for one 16-q subtile (macro: keeps all indexing
// compile-time-static; rule #20).  Uses kernel-scope: quad, l16, srcA, srcB,
// q1v, SCALE2, MASKED2, ex2.  S is f32x4[4] (clobbered), MR/LPV scalars,
// OACC f32x4[8], MW u64 mask word, AK0/AK1 output unions (keys 0-31/32-63).
// ---------------------------------------------------------------------------
#define SM_AND_P(S, MR, LPV, OACC, MW, AK0, AK1)                               \
  do {                                                                         \
    const unsigned mlo_ = (unsigned)(MW);                                      \
    const unsigned mhi_ = (unsigned)((MW) >> 32);                              \
    const int gq_ = quad << 2;                                                 \
    const unsigned fm_0 = mlo_ >> gq_, fm_1 = (mlo_ >> 16) >> gq_;             \
    const unsigned fm_2 = mhi_ >> gq_, fm_3 = (mhi_ >> 16) >> gq_;             \
    _Pragma("unroll")                                                          \
    for (int r_ = 0; r_ < 4; ++r_) {                                           \
      S[0][r_] = (fm_0 & (1u << r_)) ? S[0][r_] * SCALE2 : MASKED2;            \
      S[1][r_] = (fm_1 & (1u << r_)) ? S[1][r_] * SCALE2 : MASKED2;            \
      S[2][r_] = (fm_2 & (1u << r_)) ? S[2][r_] * SCALE2 : MASKED2;            \
      S[3][r_] = (fm_3 & (1u << r_)) ? S[3][r_] * SCALE2 : MASKED2;            \
    }                                                                          \
    float mt_;                                                                 \
    {                                                                          \
      float a0_ = fmaxf(fmaxf(S[0][0], S[0][1]), fmaxf(S[0][2], S[0][3]));     \
      float a1_ = fmaxf(fmaxf(S[1][0], S[1][1]), fmaxf(S[1][2], S[1][3]));     \
      float a2_ = fmaxf(fmaxf(S[2][0], S[2][1]), fmaxf(S[2][2], S[2][3]));     \
      float a3_ = fmaxf(fmaxf(S[3][0], S[3][1]), fmaxf(S[3][2], S[3][3]));     \
      mt_ = fmaxf(fmaxf(a0_, a1_), fmaxf(a2_, a3_));                           \
    }                                                                          \
    mt_ = fmaxf(mt_, __shfl_xor(mt_, 16));                                     \
    mt_ = fmaxf(mt_, __shfl_xor(mt_, 32));                                     \
    const bool res_ = (mt_ > (MR) + 8.0f);                                     \
    if (__any(res_)) {                                                         \
      const float mn_ = res_ ? mt_ : (MR);                                     \
      const float alq_ = ex2((MR) - mn_);                                      \
      MR = mn_;                                                                \
      LPV *= alq_;                                                             \
      float alo_0 = __shfl(alq_, quad * 20 + 0);                               \
      float alo_1 = __shfl(alq_, quad * 20 + 1);                               \
      float alo_2 = __shfl(alq_, quad * 20 + 2);                               \
      float alo_3 = __shfl(alq_, quad * 20 + 3);                               \
      _Pragma("unroll")                                                        \
      for (int nc_ = 0; nc_ < 8; ++nc_) {                                      \
        OACC[nc_][0] *= alo_0; OACC[nc_][1] *= alo_1;                          \
        OACC[nc_][2] *= alo_2; OACC[nc_][3] *= alo_3;                          \
      }                                                                        \
    }                                                                          \
    {                                                                          \
      float t0_ = 0.f, t1_ = 0.f;                                              \
      _Pragma("unroll")                                                        \
      for (int nt_ = 0; nt_ < 4; ++nt_) {                                      \
        float p0_ = ex2(S[nt_][0] - (MR));                                     \
        float p1_ = ex2(S[nt_][1] - (MR));                                     \
        float p2_ = ex2(S[nt_][2] - (MR));                                     \
        float p3_ = ex2(S[nt_][3] - (MR));                                     \
        S[nt_][0] = p0_; S[nt_][1] = p1_;                                      \
        S[nt_][2] = p2_; S[nt_][3] = p3_;                                      \
        t0_ += p0_ + p1_; t1_ += p2_ + p3_;                                    \
      }                                                                        \
      LPV += t0_ + t1_;                                                        \
    }                                                                          \
    int pk00_, pk01_, pk10_, pk11_, pk20_, pk21_, pk30_, pk31_;                \
    asm("v_cvt_pk_bf16_f32 %0, %1, %2" : "=v"(pk00_) : "v"(S[0][0]), "v"(S[0][1])); \
    asm("v_cvt_pk_bf16_f32 %0, %1, %2" : "=v"(pk01_) : "v"(S[0][2]), "v"(S[0][3])); \
    asm("v_cvt_pk_bf16_f32 %0, %1, %2" : "=v"(pk10_) : "v"(S[1][0]), "v"(S[1][1])); \
    asm("v_cvt_pk_bf16_f32 %0, %1, %2" : "=v"(pk11_) : "v"(S[1][2]), "v"(S[1][3])); \
    asm("v_cvt_pk_bf16_f32 %0, %1, %2" : "=v"(pk20_) : "v"(S[2][0]), "v"(S[2][1])); \
    asm("v_cvt_pk_bf16_f32 %0, %1, %2" : "=v"(pk21_) : "v"(S[2][2]), "v"(S[2][3])); \
    asm("v_cvt_pk_bf16_f32 %0, %1, %2" : "=v"(pk30_) : "v"(S[3][0]), "v"(S[3][1])); \
    asm("v_cvt_pk_bf16_f32 %0, %1, %2" : "=v"(pk31_) : "v"(S[3][2]), "v"(S[3][3])); \
    {                                                                          \
      int u0_, u1_;                                                            \
      u0_ = __shfl(pk00_, srcA); u1_ = __shfl(pk10_, srcA); AK0.d[0] = q1v ? u1_ : u0_; \
      u0_ = __shfl(pk01_, srcA); u1_ = __shfl(pk11_, srcA); AK0.d[1] = q1v ? u1_ : u0_; \
      u0_ = __shfl(pk00_, srcB); u1_ = __shfl(pk10_, srcB); AK0.d[2] = q1v ? u1_ : u0_; \
      u0_ = __shfl(pk01_, srcB); u1_ = __shfl(pk11_, srcB); AK0.d[3] = q1v ? u1_ : u0_; \
      u0_ = __shfl(pk20_, srcA); u1_ = __shfl(pk30_, srcA); AK1.d[0] = q1v ? u1_ : u0_; \
      u0_ = __shfl(pk21_, srcA); u1_ = __shfl(pk31_, srcA); AK1.d[1] = q1v ? u1_ : u0_; \
      u0_ = __shfl(pk20_, srcB); u1_ = __shfl(pk30_, srcB); AK1.d[2] = q1v ? u1_ : u0_; \
      u0_ = __shfl(pk21_, srcB); u1_ = __shfl(pk31_, srcB); AK1.d[3] = q1v ? u1_ : u0_; \
    }                                                                          \
  } while (0)

// ---------------------------------------------------------------------------
// MFMA flash attention — R9: R7 structure (32 q/wave, two 16-q subtiles,
// shared K/V fragment reads, 2 blocks/CU) + R8's safe additions (bf16 Q
// hi/lo direct loads from QOUT GEMM epilogue; in-loop mask loads with the
// verified vmcnt ledger).  launch_bounds REVERTED to (256,2): R5 proved the
// register budget (Q 64 + O 64 + S 32 + frags) spills at 3 waves/EU
// (FETCH 81MB -> 1.96GB scratch traffic, MfmaUtil 28 -> 8).
// vmcnt ledger: A-wait vmcnt(4) [K(t)x8 oldest drained, V(t)x4 remain];
// mask x2 issued after A; pre-softmax vmcnt(8) drains V+mask, leaves
// K(t+1)x8 in flight.
// ---------------------------------------------------------------------------
__global__ __launch_bounds__(256, 2)
void attn_mfma(const short* __restrict__ Qhi_g, const short* __restrict__ Qlo_g,
               const short* __restrict__ Khi_g, const short* __restrict__ Klo_g,
               const short* __restrict__ Vt_g,
               const unsigned long long* __restrict__ Mb, short* __restrict__ AObf)
{
    __shared__ short KhiS[64 * 128];
    __shared__ short KloS[64 * 128];
    __shared__ short VtS [128 * 64];

    // XCD-aware swizzle: all 16 q-blocks of one (b,h) group land on the same
    // XCD (fid%8), so its K/V (1.5 MB) stays resident in that XCD's 4 MB L2.
    const int fid  = blockIdx.x + 16 * (blockIdx.y + 16 * blockIdx.z);
    const int slot = fid >> 3;                       // 0..127
    const int grp  = (fid & 7) + 8 * (slot >> 4);    // 0..63 = (b,h)
    const int qb   = slot & 15;                      // 0..15 (128-q block)
    const int h    = grp & 15;
    const int bb   = grp >> 4;

    const int t    = threadIdx.x;
    const int w    = t >> 6;     // wave 0..3
    const int L    = t & 63;
    const int l16  = L & 15;
    const int quad = L >> 4;
    const int q1v  = quad >> 1;
    const int kh   = h & (NKVc - 1);     // jnp.tile: head h -> kv-head h%4
    const int tq0  = qb * 128 + w * 16;          // subtile 0 q-base
    const int tq1  = tq0 + 64;                   // subtile 1 q-base

    // ---- Q fragments for both subtiles: direct bf16 hi/lo vector loads ----
    bf16x8 qhi0[4], qlo0[4], qhi1[4], qlo1[4];
    {
        const size_t qoff = (size_t)(bb * Tc + h * HDc + qb * 8 + w) * Ec
                          + 128 * l16 + quad * 8;
        const short* qh = Qhi_g + qoff;
        const short* ql = Qlo_g + qoff;
        #pragma unroll
        for (int kc = 0; kc < 4; ++kc) {
            qhi0[kc] = *(const bf16x8*)(qh + kc * 32);
            qlo0[kc] = *(const bf16x8*)(ql + kc * 32);
            qhi1[kc] = *(const bf16x8*)(qh + (size_t)4 * Ec + kc * 32);
            qlo1[kc] = *(const bf16x8*)(ql + (size_t)4 * Ec + kc * 32);
        }
    }

    // per-lane online-softmax state (subtile 0 and 1)
    float m0 = -INFINITY, lp0 = 0.0f;
    float m1 = -INFINITY, lp1 = 0.0f;
    f32x4 o0[8], o1[8];
    #pragma unroll
    for (int nc = 0; nc < 8; ++nc) {
        o0[nc] = (f32x4){0, 0, 0, 0};
        o1[nc] = (f32x4){0, 0, 0, 0};
    }

    const short* kbh = Khi_g + ((size_t)(bb * NKVc + kh)) * Tc * HDc;
    const short* kbl = Klo_g + ((size_t)(bb * NKVc + kh)) * Tc * HDc;
    const short* vb  = Vt_g  + ((size_t)(bb * NKVc + kh)) * HDc * Tc;
    const unsigned long long* mrow0 =
        Mb + ((size_t)(bb * Tc + tq0 + l16)) * (Tc / 64);
    const unsigned long long* mrow1 = mrow0 + (size_t)64 * (Tc / 64);

    constexpr float SCALE2  = 11.313708498984761f * 1.4426950408889634f;
    constexpr float MASKED2 = 1e-9f * 1.4426950408889634f;

    // staging lane decode
    const int km   = L >> 4;
    const int kpos = L & 15;
    const int vm   = L >> 3;
    const int vc   = ((L & 7) - vm) & 7;

    // shuffle source lanes for P redistribution (same l16, quad remap)
    const int srcA = l16 + 16 * ((2 * quad)     & 3);
    const int srcB = l16 + 16 * ((2 * quad + 1) & 3);

    // 8 vmcnt events per call, wave w stages wl = 4w..4w+3
    auto stageK = [&](int kt) {
        #pragma unroll
        for (int i = 0; i < 4; ++i) {
            const int wl = w * 4 + i;
            const int krow = wl * 4 + km;
            const int kc_ = (kpos - (krow & 15)) & 15;
            const size_t go = (size_t)(kt * 64 + krow) * HDc + kc_ * 8;
            gload16(kbh + go, &KhiS[wl * 512]);
            gload16(kbl + go, &KloS[wl * 512]);
        }
    };
    // 4 vmcnt events per call
    auto stageV = [&](int kt) {
        #pragma unroll
        for (int i = 0; i < 4; ++i) {
            const int wl = w * 4 + i;
            const int vrow = wl * 8 + vm;
            gload16(vb + (size_t)vrow * Tc + kt * 64 + vc * 8, &VtS[wl * 512]);
        }
    };

    // ---- prologue: drain Q loads so staging vmcnt arithmetic is exact ----
    asm volatile("s_waitcnt vmcnt(0)" ::: "memory");
    __builtin_amdgcn_sched_barrier(0);
    stageK(0);
    __builtin_amdgcn_sched_barrier(0);
    stageV(0);
    __builtin_amdgcn_sched_barrier(0);

    union U { int d[4]; bf16x8 v; };

    for (int kt = 0; kt < Tc / 64; ++kt) {
        const int ktn = (kt + 1) & 31;   // wrap: tile-0 re-stage is harmless

        // A: own K(t) landed (leaves V x4 in flight), then all-waves sync
        asm volatile("s_waitcnt vmcnt(4)" ::: "memory");
        __builtin_amdgcn_s_barrier();
        __builtin_amdgcn_sched_barrier(0);

        // mask words for THIS tile — land under QK^T (L2-hot: shared by all
        // 16 heads of the same (b,q) rows)
        const unsigned long long mw0 = mrow0[kt];
        const unsigned long long mw1 = mrow1[kt];

        // ---- swapped QK^T for BOTH subtiles, K-fragments read once ----
        f32x4 s0[4], s1[4];
        #pragma unroll
        for (int nt = 0; nt < 4; ++nt) {
            f32x4 a0 = (f32x4){0, 0, 0, 0};
            f32x4 a1 = (f32x4){0, 0, 0, 0};
            #pragma unroll
            for (int kc = 0; kc < 4; ++kc) {
                const int ch = (((nt * 4 + (l16 >> 2)) << 6) + ((l16 & 3) << 4)
                                + ((kc * 4 + quad + l16) & 15)) << 3;
                bf16x8 khiF = *(const bf16x8*)&KhiS[ch];
                bf16x8 kloF = *(const bf16x8*)&KloS[ch];
                a0 = __builtin_amdgcn_mfma_f32_16x16x32_bf16(khiF, qhi0[kc], a0, 0, 0, 0);
                a0 = __builtin_amdgcn_mfma_f32_16x16x32_bf16(khiF, qlo0[kc], a0, 0, 0, 0);
                a0 = __builtin_amdgcn_mfma_f32_16x16x32_bf16(kloF, qhi0[kc], a0, 0, 0, 0);
                a1 = __builtin_amdgcn_mfma_f32_16x16x32_bf16(khiF, qhi1[kc], a1, 0, 0, 0);
                a1 = __builtin_amdgcn_mfma_f32_16x16x32_bf16(khiF, qlo1[kc], a1, 0, 0, 0);
                a1 = __builtin_amdgcn_mfma_f32_16x16x32_bf16(kloF, qhi1[kc], a1, 0, 0, 0);
            }
            s0[nt] = a0;
            s1[nt] = a1;
        }

        // E: all waves done reading K buffers -> safe to overwrite
        asm volatile("s_waitcnt lgkmcnt(0)" ::: "memory");
        __builtin_amdgcn_sched_barrier(0);
        __builtin_amdgcn_s_barrier();
        __builtin_amdgcn_sched_barrier(0);
        // F: prefetch next K (flies under softmax + PV)
        stageK(ktn);
        __builtin_amdgcn_sched_barrier(0);

        // drain own V(t) + mask (oldest 6); K(t+1) x8 stay in flight
        asm volatile("s_waitcnt vmcnt(8)" ::: "memory");

        // ---- softmax + P->A-fragments, per subtile ----
        U A00, A01, A10, A11;
        SM_AND_P(s0, m0, lp0, o0, mw0, A00, A01);
        SM_AND_P(s1, m1, lp1, o1, mw1, A10, A11);

        // H: all waves have drained their V loads (vmcnt(8) above) -> sync
        __builtin_amdgcn_s_barrier();
        __builtin_amdgcn_sched_barrier(0);

        // ---- PV for BOTH subtiles, V-fragments read once ----
        #pragma unroll
        for (int nc = 0; nc < 8; ++nc) {
            const int rg = (nc * 2 + (l16 >> 3)) << 6;
            const int rm = l16 & 7;
            const int ch0 = (rg + (rm << 3) + ((quad + rm) & 7)) << 3;
            const int ch1 = (rg + (rm << 3) + ((quad + 4 + rm) & 7)) << 3;
            bf16x8 b0 = *(const bf16x8*)&VtS[ch0];
            bf16x8 b1 = *(const bf16x8*)&VtS[ch1];
            o0[nc] = __builtin_amdgcn_mfma_f32_16x16x32_bf16(A00.v, b0, o0[nc], 0, 0, 0);
            o0[nc] = __builtin_amdgcn_mfma_f32_16x16x32_bf16(A01.v, b1, o0[nc], 0, 0, 0);
            o1[nc] = __builtin_amdgcn_mfma_f32_16x16x32_bf16(A10.v, b0, o1[nc], 0, 0, 0);
            o1[nc] = __builtin_amdgcn_mfma_f32_16x16x32_bf16(A11.v, b1, o1[nc], 0, 0, 0);
        }

        // K: all waves done reading VtS -> safe to overwrite
        asm volatile("s_waitcnt lgkmcnt(0)" ::: "memory");
        __builtin_amdgcn_sched_barrier(0);
        __builtin_amdgcn_s_barrier();
        __builtin_amdgcn_sched_barrier(0);
        // L: prefetch next V (flies under next QK^T)
        stageV(ktn);
        __builtin_amdgcn_sched_barrier(0);
    }

    // drain outstanding prefetch DMA before the block can retire
    asm volatile("s_waitcnt vmcnt(0)" ::: "memory");

    // ---- final l reduction across quads, then write both subtiles ----
    lp0 += __shfl_xor(lp0, 16);
    lp0 += __shfl_xor(lp0, 32);
    lp1 += __shfl_xor(lp1, 16);
    lp1 += __shfl_xor(lp1, 32);
    const float invl0 = 1.0f / lp0;
    const float invl1 = 1.0f / lp1;
    float invo0[4], invo1[4];
    #pragma unroll
    for (int r = 0; r < 4; ++r) {
        invo0[r] = __shfl(invl0, quad * 16 + quad * 4 + r);
        invo1[r] = __shfl(invl1, quad * 16 + quad * 4 + r);
    }

    #pragma unroll
    for (int r = 0; r < 4; ++r) {
        short* orow = AObf + ((size_t)(bb * Tc + tq0 + quad * 4 + r)) * Ec
                           + h * HDc + l16;
        #pragma unroll
        for (int nc = 0; nc < 8; ++nc)
            orow[nc * 16] = f2bf(o0[nc][r] * invo0[r]);
    }
    #pragma unroll
    for (int r = 0; r < 4; ++r) {
        short* orow = AObf + ((size_t)(bb * Tc + tq1 + quad * 4 + r)) * Ec
                           + h * HDc + l16;
        #pragma unroll
        for (int nc = 0; nc < 8; ++nc)
            orow[nc * 16] = f2bf(o1[nc][r] * invo1[r]);
    }
}

// ---------------------------------------------------------------------------
// Launch
// ---------------------------------------------------------------------------
extern "C" void kernel_launch(void* const* d_in, const int* in_sizes, int n_in,
                              void* d_out, int out_size, void* d_ws, size_t ws_size,
                              hipStream_t stream)
{
    const float* x    = (const float*)d_in[0];
    const int*  amask = (const int*)  d_in[1];
    const float* Wq   = (const float*)d_in[2];
    const float* bq   = (const float*)d_in[3];
    const float* Wk   = (const float*)d_in[4];
    const float* bk   = (const float*)d_in[5];
    const float* Wv   = (const float*)d_in[6];
    const float* bv   = (const float*)d_in[7];
    const float* Wo   = (const float*)d_in[8];
    const float* bo   = (const float*)d_in[9];
    float* out = (float*)d_out;

    // Workspace layout (bytes), 160 MiB + 2 MiB bitmask:
    //  [0,   32M)  Qhi bf16   [32M,64M) Qlo bf16  (Q-GEMM split epilogue)
    //  [64M, 96M)  Xhi bf16            -> AObf bf16 (after V-GEMM)
    //  [96M,128M)  Xlo bf16            -> V2d fp32 [96M,112M) + Khi/Klo [112M,128M)
    //  [128M,144M) WqT hi+lo           -> WkT hi/lo + WvT + WoT (after Q-GEMM)
    //  [144M,160M) K2d fp32            -> Vt bf16 (after rope_k)
    //  [160M,162M) Mbits u64
    char* ws = (char*)d_ws;
    short* Qhi   = (short*)(ws);
    short* Qlo   = (short*)(ws + 33554432);
    short* Xhi   = (short*)(ws + 67108864);
    short* Xlo   = (short*)(ws + 100663296);
    short* WqThi = (short*)(ws + 134217728);
    short* WqTlo = (short*)(ws + 134217728 + 8388608);
    float* K2d   = (float*)(ws + 150994944);
    // overlays:
    float* V2d   = (float*)(ws + 100663296);              // over Xlo[0:16M)
    short* Khi   = (short*)(ws + 100663296 + 16777216);   // over Xlo[16M:24M)
    short* Klo   = (short*)(ws + 100663296 + 25165824);   // over Xlo[24M:32M)
    short* WkThi = (short*)(ws + 134217728);              // over WqT after Q-GEMM
    short* WkTlo = (short*)(ws + 134217728 + 2097152);
    short* WvThi = (short*)(ws + 134217728 + 4194304);
    short* WoThi = (short*)(ws + 134217728 + 8388608);
    short* Vt    = (short*)(ws + 150994944);              // over K2d after rope_k
    short* AObf  = (short*)(ws + 67108864);               // over Xhi after V-GEMM
    unsigned long long* Mb = (unsigned long long*)(ws + 167772160);

    const int M = Bc * Tc;      // 8192
    dim3 blk(256);

    // 0) mask -> bitmask (B*T*T/64 = 262144 words, 4 words/block)
    mask_bits<<<(Bc * Tc * (Tc / 64)) / 4, blk, 0, stream>>>(amask, Mb);
    // 1) Wq^T split, x split
    transpose_split<<<dim3(Ec / 32, Ec / 32), blk, 0, stream>>>(Wq, WqThi, WqTlo, Ec, Ec);
    convert_split<<<(M * Ec / 4) / 256, blk, 0, stream>>>(x, Xhi, Xlo);
    // 2) Q projection (split, fp32-fidelity, bf16 hi/lo output)
    gemm_mfma<true, true><<<dim3(M / 128, Ec / 128), blk, 0, stream>>>(
        Xhi, Xlo, WqThi, WqTlo, bq, nullptr, Qhi, Qlo, M, Ec, Ec);
    // 3) remaining weight transposes (into the now-dead WqT slab)
    transpose_split<<<dim3(Ec / 32, KVEc / 32), blk, 0, stream>>>(Wk, WkThi, WkTlo, Ec, KVEc);
    transpose_split<<<dim3(Ec / 32, KVEc / 32), blk, 0, stream>>>(Wv, WvThi, nullptr, Ec, KVEc);
    transpose_split<<<dim3(Ec / 32, Ec / 32), blk, 0, stream>>>(Wo, WoThi, nullptr, Ec, Ec);
    // 4) K projection (split), V projection (plain)
    gemm_mfma<true, false><<<dim3(M / 128, KVEc / 128), blk, 0, stream>>>(
        Xhi, Xlo, WkThi, WkTlo, bk, K2d, nullptr, nullptr, M, KVEc, Ec);
    gemm_mfma<false, false><<<dim3(M / 128, KVEc / 128), blk, 0, stream>>>(
        Xhi, nullptr, WvThi, nullptr, bv, V2d, nullptr, nullptr, M, KVEc, Ec);
    // 5) RoPE: K -> hi/lo bf16, V -> transposed bf16
    rope_k<<<(Bc * NKVc * Tc * 64) / 256, blk, 0, stream>>>(K2d, Khi, Klo);
    rope_v_t<<<dim3(Tc / 32, NKVc, Bc), blk, 0, stream>>>(V2d, Vt);
    // 6) attention (256 threads, 128 q-rows/block, 32 q/wave) -> bf16 AO
    attn_mfma<<<dim3(Tc / 128, NHc, Bc), blk, 0, stream>>>(
        Qhi, Qlo, Khi, Klo, Vt, Mb, AObf);
    // 7) output projection (plain)
    gemm_mfma<false, false><<<dim3(M / 128, Ec / 128), blk, 0, stream>>>(
        AObf, nullptr, WoThi, nullptr, bo, out, nullptr, nullptr, M, Ec, Ec);
}